// Round 13
// baseline (87.703 us; speedup 1.0000x reference)
//
#include <hip/hip_runtime.h>

typedef unsigned int uint;

#define B_ 2
#define C_ 128
#define H_ 96
#define W_ 96
#define HEADS_ 4
#define HD_ 32
#define M_ 16
#define WIN_ 7
#define PAD_ 3
#define N_ (H_*W_)              // 9216
#define HP_ (H_+2*PAD_)         // 102
#define HP2_ (HP_*HP_)          // 10404
#define KW_ (WIN_*WIN_)         // 49
#define TILE_ 8                 // attn tile is 8x8 pixels
#define HALO_ (TILE_+WIN_-1)    // 14
#define NHALO_ (HALO_*HALO_)    // 196

static __device__ __forceinline__ uint f2bf(float f) {
    uint u = __float_as_uint(f);
    u = (u + 0x7fffu + ((u >> 16) & 1u)) >> 16;   // RNE to bf16 (integer, mode-independent)
    return u & 0xffffu;
}
static __device__ __forceinline__ uint pack2(float a, float b) {
    return f2bf(a) | (f2bf(b) << 16);
}
static __device__ __forceinline__ float bf_lo(uint u){ return __uint_as_float(u << 16); }
static __device__ __forceinline__ float bf_hi(uint u){ return __uint_as_float(u & 0xffff0000u); }

// HW bf16 pair-dot: D = a.bf16[0]*b.bf16[0] + a.bf16[1]*b.bf16[1] + c  (1 inst)
static __device__ __forceinline__ float dot2bf(uint a, uint b, float c) {
    float d;
    asm("v_dot2_f32_bf16 %0, %1, %2, %3" : "=v"(d) : "v"(a), "v"(b), "v"(c));
    return d;
}

// Intra-quad cross-lane via DPP quad_perm (VALU pipe) instead of __shfl_*.
template<int CTRL>
static __device__ __forceinline__ float dpp_mov(float v) {
    return __int_as_float(__builtin_amdgcn_update_dpp(
        0, __float_as_int(v), CTRL, 0xF, 0xF, false));
}
#define DPP_XOR1(v)  dpp_mov<0xB1>(v)   // [1,0,3,2]
#define DPP_XOR2(v)  dpp_mov<0x4E>(v)   // [2,3,0,1]
#define DPP_BCAST0(v) dpp_mov<0x00>(v)
#define DPP_BCAST1(v) dpp_mov<0x55>(v)
#define DPP_BCAST2(v) dpp_mov<0xAA>(v)
#define DPP_BCAST3(v) dpp_mov<0xFF>(v)

// ---------------------------------------------------------------------------
// KVp layout (head-major, K/V interleaved, bf16 pairs):
//   KVp[((b*HEADS+h)*HP2 + row)*32 + u], u<16: K pair u, u>=16: V pair u-16.
// AOu layout: [B][N][64] bf16 pairs (attn output, packed along channels).
// ---------------------------------------------------------------------------

// Kernel 1: fill padded borders of KVp with bias (= proj of zero input), and
// build PhiT: [B][102][102][16] fp32, border = 1.0
__global__ __launch_bounds__(256) void pad_fill(
    const float* __restrict__ phi, const float* __restrict__ bk, const float* __restrict__ bv,
    uint* __restrict__ KVp, float* __restrict__ PhiT)
{
    int idx = blockIdx.x * 256 + threadIdx.x;
    if (idx >= B_*HP2_) return;
    int b  = idx / HP2_;
    int pp = idx % HP2_;
    int py = pp / HP_, px = pp % HP_;
    bool interior = (py >= PAD_ && py < H_+PAD_ && px >= PAD_ && px < W_+PAD_);
    if (!interior) {
        #pragma unroll
        for (int h = 0; h < HEADS_; ++h) {
            size_t base = ((size_t)(b*HEADS_+h)*HP2_ + pp) * 32;
            #pragma unroll
            for (int q4i = 0; q4i < 4; ++q4i) {
                const float* kb8 = bk + h*HD_ + q4i*8;
                const float* vb8 = bv + h*HD_ + q4i*8;
                uint4 ku, vu;
                ku.x = pack2(kb8[0],kb8[1]); ku.y = pack2(kb8[2],kb8[3]);
                ku.z = pack2(kb8[4],kb8[5]); ku.w = pack2(kb8[6],kb8[7]);
                vu.x = pack2(vb8[0],vb8[1]); vu.y = pack2(vb8[2],vb8[3]);
                vu.z = pack2(vb8[4],vb8[5]); vu.w = pack2(vb8[6],vb8[7]);
                ((uint4*)(KVp + base))[q4i]     = ku;
                ((uint4*)(KVp + base))[4 + q4i] = vu;
            }
        }
    }
    size_t pb = ((size_t)b*HP2_ + pp) * M_;
    if (interior) {
        int y = py - PAD_, xx = px - PAD_;
        #pragma unroll
        for (int m = 0; m < M_; ++m)
            PhiT[pb + m] = phi[((size_t)b*M_ + m)*N_ + y*W_ + xx];
    } else {
        #pragma unroll
        for (int m = 0; m < M_; ++m) PhiT[pb + m] = 1.0f;
    }
}

// ---------------------------------------------------------------------------
// Kernel 2: Q/K/V projection as a K-paired bf16 dot2 GEMM.
// ---------------------------------------------------------------------------
__global__ __launch_bounds__(256, 2) void qkv_proj(
    const float* __restrict__ x,
    const float* __restrict__ Wq, const float* __restrict__ bq,
    const float* __restrict__ Wk, const float* __restrict__ bk,
    const float* __restrict__ Wv, const float* __restrict__ bv,
    float* __restrict__ Qp, uint* __restrict__ KVp)
{
    __shared__ uint ldsX[64*128];   // [ci2][pix] bf16 pairs (32 KB)
    __shared__ uint ldsW[64*128];   // [ci2][co]  bf16 pairs (32 KB)

    const int t  = threadIdx.x;
    const int n0 = blockIdx.x * 128;
    const int b  = blockIdx.y;
    const int pj = blockIdx.z;
    const float* Wsrc = (pj == 0) ? Wq : (pj == 1) ? Wk : Wv;
    const float* bsrc = (pj == 0) ? bq : (pj == 1) ? bk : bv;

    // stage X: pack (x[2ci2], x[2ci2+1]) along K; coalesced over pix
    for (int idx = t; idx < 64*128; idx += 256) {
        int ci2 = idx >> 7, pix = idx & 127;
        float a = x[((size_t)b*C_ + 2*ci2    )*N_ + n0 + pix];
        float c = x[((size_t)b*C_ + 2*ci2 + 1)*N_ + n0 + pix];
        ldsX[idx] = pack2(a, c);
    }
    // stage W: pack (w[2ci2][co], w[2ci2+1][co]); coalesced over co
    for (int idx = t; idx < 64*128; idx += 256) {
        int ci2 = idx >> 7, co = idx & 127;
        ldsW[idx] = pack2(Wsrc[(size_t)(2*ci2)*C_ + co],
                          Wsrc[(size_t)(2*ci2+1)*C_ + co]);
    }
    __syncthreads();

    const int co_g  = t & 15;    // co  = co_g*8 .. +7
    const int pix_g = t >> 4;    // pix = pix_g*8 .. +7
    const int co0   = co_g * 8;

    float acc[8][8];             // [co][pix], literal-indexed only
    #pragma unroll
    for (int i = 0; i < 8; ++i) {
        float bi = bsrc[co0 + i];
        #pragma unroll
        for (int j = 0; j < 8; ++j) acc[i][j] = bi;
    }

    for (int ci2 = 0; ci2 < 64; ++ci2) {
        uint4 xv0 = *(const uint4*)&ldsX[ci2*128 + pix_g*8];
        uint4 xv1 = *(const uint4*)&ldsX[ci2*128 + pix_g*8 + 4];
        uint4 wv0 = *(const uint4*)&ldsW[ci2*128 + co0];
        uint4 wv1 = *(const uint4*)&ldsW[ci2*128 + co0 + 4];
        uint xa[8] = {xv0.x, xv0.y, xv0.z, xv0.w, xv1.x, xv1.y, xv1.z, xv1.w};
        uint wa[8] = {wv0.x, wv0.y, wv0.z, wv0.w, wv1.x, wv1.y, wv1.z, wv1.w};
        #pragma unroll
        for (int i = 0; i < 8; ++i)
            #pragma unroll
            for (int j = 0; j < 8; ++j)
                acc[i][j] = dot2bf(wa[i], xa[j], acc[i][j]);
    }

    if (pj == 0) {
        #pragma unroll
        for (int j = 0; j < 8; ++j) {
            int n = n0 + pix_g*8 + j;
            float* qo = Qp + ((size_t)b*N_ + n)*C_ + co0;
            *(float4*)(qo    ) = make_float4(acc[0][j], acc[1][j], acc[2][j], acc[3][j]);
            *(float4*)(qo + 4) = make_float4(acc[4][j], acc[5][j], acc[6][j], acc[7][j]);
        }
    } else {
        const int h     = co0 >> 5;
        const int u0    = ((pj == 1) ? 0 : 16) + ((co0 & 31) >> 1);
        uint* kvb = KVp + (size_t)(b*HEADS_+h)*HP2_*32;
        #pragma unroll
        for (int j = 0; j < 8; ++j) {
            int n = n0 + pix_g*8 + j;
            int y = n / W_, xx = n % W_;
            size_t rowb = (size_t)(y+PAD_)*HP_ + (xx+PAD_);
            uint4 uu;
            uu.x = pack2(acc[0][j], acc[1][j]);
            uu.y = pack2(acc[2][j], acc[3][j]);
            uu.z = pack2(acc[4][j], acc[5][j]);
            uu.w = pack2(acc[6][j], acc[7][j]);
            *(uint4*)(kvb + rowb*32 + u0) = uu;
        }
    }
}

// ---------------------------------------------------------------------------
// Kernel 3: local attention, 4 threads per (pixel, head).
// QK on v_dot2_f32_bf16 with COMPENSATED q (hi+lo bf16, integer RNE pack).
// Output written as packed bf16 pairs (AOu) to feed the dot2 out_proj.
// ---------------------------------------------------------------------------
__global__ __launch_bounds__(256, 3) void attn(
    const float* __restrict__ Qp, const uint* __restrict__ KVp,
    const float* __restrict__ PhiT, const float* __restrict__ log_alpha,
    const float* __restrict__ beta, uint* __restrict__ AOu)
{
    __shared__ uint4  kl[NHALO_*4];   // 12544 B
    __shared__ uint4  vl[NHALO_*4];   // 12544 B
    __shared__ float4 pl[NHALO_*4];   // 12544 B

    const int t  = threadIdx.x;
    const int h  = blockIdx.y;
    const int b  = blockIdx.z;
    const int bx = blockIdx.x;
    const int tile = ((bx & 7) * 18) + (bx >> 3);   // 144 = 8*18, bijective
    const int y0 = (tile / (W_/TILE_)) * TILE_;
    const int x0 = (tile % (W_/TILE_)) * TILE_;

    // stage K/V halo: one full 128B line per (row, head)
    const uint* kvb = KVp + (size_t)(b*HEADS_+h)*HP2_*32;
    for (int idx = t; idx < NHALO_*8; idx += 256) {
        int hp = idx >> 3, u4 = idx & 7;
        int hy = hp / HALO_, hx = hp % HALO_;
        size_t rowb = (size_t)(y0+hy)*HP_ + (x0+hx);
        uint4 val = *(const uint4*)(kvb + rowb*32 + u4*4);
        if (u4 < 4) kl[hp*4 + u4] = val;
        else        vl[hp*4 + (u4-4)] = val;
    }
    // stage phi halo (fp32)
    const float* pbase = PhiT + (size_t)b*HP2_*M_;
    for (int idx = t; idx < NHALO_*4; idx += 256) {
        int hp = idx >> 2, sb = idx & 3;
        int hy = hp / HALO_, hx = hp % HALO_;
        size_t rowb = (size_t)(y0+hy)*HP_ + (x0+hx);
        pl[idx] = *(const float4*)(pbase + rowb*M_ + sb*4);
    }
    __syncthreads();

    const int s  = t & 3;       // sub-lane: channels s*8.., phi dims s*4..
    const int p  = t >> 2;      // pixel 0..63
    const int qy = p >> 3, qx = p & 7;
    const int n  = (y0+qy)*W_ + (x0+qx);
    const bool c1 = (s & 1) != 0;
    const bool c2 = (s & 2) != 0;

    // q: load fp32; split q = q_hi + q_lo (both bf16, integer RNE pack).
    uint qh0, qh1, qh2, qh3, ql0, ql1, ql2, ql3;
    {
        const float* qptr = Qp + ((size_t)b*N_ + n)*C_ + h*HD_ + s*8;
        float4 q0 = ((const float4*)qptr)[0];
        float4 q1 = ((const float4*)qptr)[1];
        float qf[8] = {q0.x, q0.y, q0.z, q0.w, q1.x, q1.y, q1.z, q1.w};
        float rf[8];
        #pragma unroll
        for (int i = 0; i < 8; ++i)
            rf[i] = qf[i] - __uint_as_float(f2bf(qf[i]) << 16);
        qh0 = pack2(qf[0], qf[1]); qh1 = pack2(qf[2], qf[3]);
        qh2 = pack2(qf[4], qf[5]); qh3 = pack2(qf[6], qf[7]);
        ql0 = pack2(rf[0], rf[1]); ql1 = pack2(rf[2], rf[3]);
        ql2 = pack2(rf[4], rf[5]); ql3 = pack2(rf[6], rf[7]);
    }
    float4 pc = pl[((qy+PAD_)*HALO_ + (qx+PAD_))*4 + s];

    const float alpha = __expf(log_alpha[0]);
    const float scale = 0.17677669529663687f;                 // HD^-0.5
    const float gcoef = -beta[h] * alpha * 0.17677669529663687f; // -beta*alpha/sqrt(2M)

    auto partial = [&](int hp) -> float {
        uint4 kw = kl[(hp<<2) + s];
        float da = dot2bf(qh0, kw.x, 0.0f);
        float db = dot2bf(ql0, kw.x, 0.0f);
        da = dot2bf(qh1, kw.y, da);
        db = dot2bf(ql1, kw.y, db);
        da = dot2bf(qh2, kw.z, da);
        db = dot2bf(ql2, kw.z, db);
        da = dot2bf(qh3, kw.w, da);
        db = dot2bf(ql3, kw.w, db);
        float pdot = da + db;
        float4 pv = pl[(hp<<2) + s];
        float d0 = pc.x - pv.x, d1 = pc.y - pv.y;
        float d2 = pc.z - pv.z, d3 = pc.w - pv.w;
        float pdsq = fmaf(d0,d0, fmaf(d1,d1, fmaf(d2,d2, d3*d3)));
        return fmaf(pdot, scale, gcoef*pdsq);
    };

    float lp[13];
    float mx = -1e30f;

#define HPOS(KK) ((qy + (KK)/WIN_)*HALO_ + qx + ((KK)%WIN_))
#define LGROUP(G) { \
    float pr0 = partial(HPOS(4*(G)  )); \
    float pr1 = partial(HPOS(4*(G)+1)); \
    float pr2 = partial(HPOS(4*(G)+2)); \
    float pr3 = partial(HPOS(4*(G)+3)); \
    float Av = (c1 ? pr1 : pr0) + DPP_XOR1(c1 ? pr0 : pr1); \
    float Bv = (c1 ? pr3 : pr2) + DPP_XOR1(c1 ? pr2 : pr3); \
    float lg = (c2 ? Bv : Av) + DPP_XOR2(c2 ? Av : Bv); \
    lp[(G)] = lg; mx = fmaxf(mx, lg); }

    LGROUP(0) LGROUP(1) LGROUP(2) LGROUP(3) LGROUP(4) LGROUP(5)
    LGROUP(6) LGROUP(7) LGROUP(8) LGROUP(9) LGROUP(10) LGROUP(11)
    {   // kk = 48: all lanes hold it; only lane s==0 "owns" it
        float pr = partial(HPOS(48));
        pr += DPP_XOR1(pr);
        pr += DPP_XOR2(pr);
        lp[12] = pr; mx = fmaxf(mx, pr);
    }
    mx = fmaxf(mx, DPP_XOR1(mx));
    mx = fmaxf(mx, DPP_XOR2(mx));

    float ssum = 0.f;
#define EXPG(G) { float e = __expf(lp[(G)] - mx); lp[(G)] = e; ssum += e; }
    EXPG(0) EXPG(1) EXPG(2) EXPG(3) EXPG(4) EXPG(5)
    EXPG(6) EXPG(7) EXPG(8) EXPG(9) EXPG(10) EXPG(11)
    {
        float e = (s == 0) ? __expf(lp[12] - mx) : 0.f;
        lp[12] = e; ssum += e;
    }
    ssum += DPP_XOR1(ssum);
    ssum += DPP_XOR2(ssum);
    float inv = 1.0f / ssum;

    float4 o0 = make_float4(0.f,0.f,0.f,0.f);
    float4 o1 = make_float4(0.f,0.f,0.f,0.f);
#define PVPOS(KK, BC) { \
    float wgt = DPP_BCAST##BC(lp[(KK)>>2]); \
    uint4 vw = vl[(HPOS(KK)<<2) + s]; \
    o0.x = fmaf(wgt, bf_lo(vw.x), o0.x); \
    o0.y = fmaf(wgt, bf_hi(vw.x), o0.y); \
    o0.z = fmaf(wgt, bf_lo(vw.y), o0.z); \
    o0.w = fmaf(wgt, bf_hi(vw.y), o0.w); \
    o1.x = fmaf(wgt, bf_lo(vw.z), o1.x); \
    o1.y = fmaf(wgt, bf_hi(vw.z), o1.y); \
    o1.z = fmaf(wgt, bf_lo(vw.w), o1.z); \
    o1.w = fmaf(wgt, bf_hi(vw.w), o1.w); }

    PVPOS(0,0)  PVPOS(1,1)  PVPOS(2,2)  PVPOS(3,3)  PVPOS(4,0)  PVPOS(5,1)  PVPOS(6,2)
    PVPOS(7,3)  PVPOS(8,0)  PVPOS(9,1)  PVPOS(10,2) PVPOS(11,3) PVPOS(12,0) PVPOS(13,1)
    PVPOS(14,2) PVPOS(15,3) PVPOS(16,0) PVPOS(17,1) PVPOS(18,2) PVPOS(19,3) PVPOS(20,0)
    PVPOS(21,1) PVPOS(22,2) PVPOS(23,3) PVPOS(24,0) PVPOS(25,1) PVPOS(26,2) PVPOS(27,3)
    PVPOS(28,0) PVPOS(29,1) PVPOS(30,2) PVPOS(31,3) PVPOS(32,0) PVPOS(33,1) PVPOS(34,2)
    PVPOS(35,3) PVPOS(36,0) PVPOS(37,1) PVPOS(38,2) PVPOS(39,3) PVPOS(40,0) PVPOS(41,1)
    PVPOS(42,2) PVPOS(43,3) PVPOS(44,0) PVPOS(45,1) PVPOS(46,2) PVPOS(47,3) PVPOS(48,0)

    // write packed bf16 pairs: AOu[b][n][h*16 + s*4 .. +4]
    uint4 uu;
    uu.x = pack2(o0.x*inv, o0.y*inv);
    uu.y = pack2(o0.z*inv, o0.w*inv);
    uu.z = pack2(o1.x*inv, o1.y*inv);
    uu.w = pack2(o1.z*inv, o1.w*inv);
    *(uint4*)(AOu + ((size_t)b*N_ + n)*64 + h*16 + s*4) = uu;
}

// ---------------------------------------------------------------------------
// Kernel 4: output projection as K-paired bf16 dot2 GEMM.
// 64 pixels/block (288 blocks -> 1 round over 256 CUs). AOu already packed
// along ci; Wo packed at stage time. Thread tile 8co x 4pix (32 fp32 acc).
// Per ci2: 3 ds_read_b128 feed 32 dot2 -> VALU-bound.
// ---------------------------------------------------------------------------
__global__ __launch_bounds__(256, 3) void out_proj(
    const uint* __restrict__ AOu, const float* __restrict__ Wo,
    const float* __restrict__ bo, float* __restrict__ out)
{
    __shared__ uint ldsX[64*64];    // [ci2][pix] (16 KB)
    __shared__ uint ldsW[64*128];   // [ci2][co]  (32 KB)

    const int t  = threadIdx.x;
    const int b  = blockIdx.x / (N_/64);
    const int n0 = (blockIdx.x % (N_/64)) * 64;

    // stage X: transpose AOu[pix][ci2] -> ldsX[ci2][pix] (uint4 load + 4 scatter)
    for (int idx = t; idx < 64*16; idx += 256) {
        int pix = idx & 63, c4 = idx >> 6;
        uint4 v = *(const uint4*)(AOu + ((size_t)b*N_ + n0 + pix)*64 + c4*4);
        ldsX[(c4*4+0)*64 + pix] = v.x;
        ldsX[(c4*4+1)*64 + pix] = v.y;
        ldsX[(c4*4+2)*64 + pix] = v.z;
        ldsX[(c4*4+3)*64 + pix] = v.w;
    }
    // stage W packed along ci pairs; coalesced over co
    for (int idx = t; idx < 64*128; idx += 256) {
        int ci2 = idx >> 7, co = idx & 127;
        ldsW[idx] = pack2(Wo[(size_t)(2*ci2)*C_ + co],
                          Wo[(size_t)(2*ci2+1)*C_ + co]);
    }
    __syncthreads();

    const int co_g  = t & 15;    // co  = co_g*8 .. +7
    const int pix_g = t >> 4;    // pix = pix_g*4 .. +3
    const int co0   = co_g * 8;

    float acc[8][4];
    #pragma unroll
    for (int i = 0; i < 8; ++i) {
        float bi = bo[co0 + i];
        #pragma unroll
        for (int j = 0; j < 4; ++j) acc[i][j] = bi;
    }

    for (int ci2 = 0; ci2 < 64; ++ci2) {
        uint4 xv  = *(const uint4*)&ldsX[ci2*64 + pix_g*4];
        uint4 wv0 = *(const uint4*)&ldsW[ci2*128 + co0];
        uint4 wv1 = *(const uint4*)&ldsW[ci2*128 + co0 + 4];
        uint xa[4] = {xv.x, xv.y, xv.z, xv.w};
        uint wa[8] = {wv0.x, wv0.y, wv0.z, wv0.w, wv1.x, wv1.y, wv1.z, wv1.w};
        #pragma unroll
        for (int i = 0; i < 8; ++i)
            #pragma unroll
            for (int j = 0; j < 4; ++j)
                acc[i][j] = dot2bf(wa[i], xa[j], acc[i][j]);
    }

    // store out[b][co][n]: one float4 (4 consecutive n) per co row
    #pragma unroll
    for (int i = 0; i < 8; ++i) {
        *(float4*)(out + ((size_t)b*C_ + co0 + i)*N_ + n0 + pix_g*4) =
            make_float4(acc[i][0], acc[i][1], acc[i][2], acc[i][3]);
    }
}

// ---------------------------------------------------------------------------
extern "C" void kernel_launch(void* const* d_in, const int* in_sizes, int n_in,
                              void* d_out, int out_size, void* d_ws, size_t ws_size,
                              hipStream_t stream)
{
    const float* x    = (const float*)d_in[0];
    const float* phi  = (const float*)d_in[1];
    const float* Wq   = (const float*)d_in[2];
    const float* bq   = (const float*)d_in[3];
    const float* Wk   = (const float*)d_in[4];
    const float* bk   = (const float*)d_in[5];
    const float* Wv   = (const float*)d_in[6];
    const float* bv   = (const float*)d_in[7];
    const float* Wo   = (const float*)d_in[8];
    const float* bo   = (const float*)d_in[9];
    const float* la   = (const float*)d_in[10];
    const float* beta = (const float*)d_in[11];
    float* out = (float*)d_out;

    // workspace layout (no aliasing: AOu is its own region).
    float* ws   = (float*)d_ws;
    float* Qp   = ws;                                        // 9.44 MB fp32
    uint*  KVp  = (uint*)(Qp + (size_t)B_*N_*C_);            // 10.65 MB
    float* PhiT = (float*)(KVp + (size_t)B_*HEADS_*HP2_*32); // 1.33 MB
    uint*  AOu  = (uint*)(PhiT + (size_t)B_*HP2_*M_);        // 4.72 MB
    
    pad_fill<<<dim3((B_*HP2_ + 255)/256), dim3(256), 0, stream>>>(phi, bk, bv, KVp, PhiT);
    qkv_proj<<<dim3(N_/128, B_, 3), dim3(256), 0, stream>>>(x, Wq, bq, Wk, bk, Wv, bv, Qp, KVp);
    attn<<<dim3((H_/TILE_)*(W_/TILE_), HEADS_, B_), dim3(256), 0, stream>>>(Qp, KVp, PhiT, la, beta, AOu);
    out_proj<<<dim3(B_*(N_/64)), dim3(256), 0, stream>>>(AOu, Wo, bo, out);
}

// Round 14
// 85.953 us; speedup vs baseline: 1.0204x; 1.0204x over previous
//
#include <hip/hip_runtime.h>

typedef unsigned int uint;

#define B_ 2
#define C_ 128
#define H_ 96
#define W_ 96
#define HEADS_ 4
#define HD_ 32
#define M_ 16
#define WIN_ 7
#define PAD_ 3
#define N_ (H_*W_)              // 9216
#define HP_ (H_+2*PAD_)         // 102
#define HP2_ (HP_*HP_)          // 10404
#define KW_ (WIN_*WIN_)         // 49
#define TILE_ 8                 // attn tile is 8x8 pixels
#define HALO_ (TILE_+WIN_-1)    // 14
#define NHALO_ (HALO_*HALO_)    // 196

static __device__ __forceinline__ uint f2bf(float f) {
    uint u = __float_as_uint(f);
    u = (u + 0x7fffu + ((u >> 16) & 1u)) >> 16;   // RNE to bf16 (integer, mode-independent)
    return u & 0xffffu;
}
static __device__ __forceinline__ uint pack2(float a, float b) {
    return f2bf(a) | (f2bf(b) << 16);
}
static __device__ __forceinline__ float bf_lo(uint u){ return __uint_as_float(u << 16); }
static __device__ __forceinline__ float bf_hi(uint u){ return __uint_as_float(u & 0xffff0000u); }

// inline function, not a macro: macro params named w/x/y/z collide with
// float4 member access under preprocessor substitution.
static __device__ __forceinline__ void fma4(float4& acc, float s, const float4& v) {
    acc.x = fmaf(s, v.x, acc.x);
    acc.y = fmaf(s, v.y, acc.y);
    acc.z = fmaf(s, v.z, acc.z);
    acc.w = fmaf(s, v.w, acc.w);
}

// HW bf16 pair-dot: D = a.bf16[0]*b.bf16[0] + a.bf16[1]*b.bf16[1] + c  (1 inst)
static __device__ __forceinline__ float dot2bf(uint a, uint b, float c) {
    float d;
    asm("v_dot2_f32_bf16 %0, %1, %2, %3" : "=v"(d) : "v"(a), "v"(b), "v"(c));
    return d;
}

// Intra-quad cross-lane via DPP quad_perm (VALU pipe) instead of __shfl_*.
template<int CTRL>
static __device__ __forceinline__ float dpp_mov(float v) {
    return __int_as_float(__builtin_amdgcn_update_dpp(
        0, __float_as_int(v), CTRL, 0xF, 0xF, false));
}
#define DPP_XOR1(v)  dpp_mov<0xB1>(v)   // [1,0,3,2]
#define DPP_XOR2(v)  dpp_mov<0x4E>(v)   // [2,3,0,1]
#define DPP_BCAST0(v) dpp_mov<0x00>(v)
#define DPP_BCAST1(v) dpp_mov<0x55>(v)
#define DPP_BCAST2(v) dpp_mov<0xAA>(v)
#define DPP_BCAST3(v) dpp_mov<0xFF>(v)

// ---------------------------------------------------------------------------
// KVp layout (head-major, K/V interleaved, bf16 pairs):
//   KVp[((b*HEADS+h)*HP2 + row)*32 + u], u<16: K pair u, u>=16: V pair u-16.
// ---------------------------------------------------------------------------

// Kernel 1: fill padded borders of KVp with bias (= proj of zero input), and
// build PhiT: [B][102][102][16] fp32, border = 1.0
__global__ __launch_bounds__(256) void pad_fill(
    const float* __restrict__ phi, const float* __restrict__ bk, const float* __restrict__ bv,
    uint* __restrict__ KVp, float* __restrict__ PhiT)
{
    int idx = blockIdx.x * 256 + threadIdx.x;
    if (idx >= B_*HP2_) return;
    int b  = idx / HP2_;
    int pp = idx % HP2_;
    int py = pp / HP_, px = pp % HP_;
    bool interior = (py >= PAD_ && py < H_+PAD_ && px >= PAD_ && px < W_+PAD_);
    if (!interior) {
        #pragma unroll
        for (int h = 0; h < HEADS_; ++h) {
            size_t base = ((size_t)(b*HEADS_+h)*HP2_ + pp) * 32;
            #pragma unroll
            for (int q4i = 0; q4i < 4; ++q4i) {
                const float* kb8 = bk + h*HD_ + q4i*8;
                const float* vb8 = bv + h*HD_ + q4i*8;
                uint4 ku, vu;
                ku.x = pack2(kb8[0],kb8[1]); ku.y = pack2(kb8[2],kb8[3]);
                ku.z = pack2(kb8[4],kb8[5]); ku.w = pack2(kb8[6],kb8[7]);
                vu.x = pack2(vb8[0],vb8[1]); vu.y = pack2(vb8[2],vb8[3]);
                vu.z = pack2(vb8[4],vb8[5]); vu.w = pack2(vb8[6],vb8[7]);
                ((uint4*)(KVp + base))[q4i]     = ku;
                ((uint4*)(KVp + base))[4 + q4i] = vu;
            }
        }
    }
    size_t pb = ((size_t)b*HP2_ + pp) * M_;
    if (interior) {
        int y = py - PAD_, xx = px - PAD_;
        #pragma unroll
        for (int m = 0; m < M_; ++m)
            PhiT[pb + m] = phi[((size_t)b*M_ + m)*N_ + y*W_ + xx];
    } else {
        #pragma unroll
        for (int m = 0; m < M_; ++m) PhiT[pb + m] = 1.0f;
    }
}

// ---------------------------------------------------------------------------
// Kernel 2: Q/K/V projection, one projection per block (grid.z = 0/1/2).
// (r11 fp32 GEMV version — best measured base.)
// ---------------------------------------------------------------------------
__global__ __launch_bounds__(256, 3) void qkv_proj(
    const float* __restrict__ x,
    const float* __restrict__ Wq, const float* __restrict__ bq,
    const float* __restrict__ Wk, const float* __restrict__ bk,
    const float* __restrict__ Wv, const float* __restrict__ bv,
    float* __restrict__ Qp, uint* __restrict__ KVp)
{
    __shared__ float4 ldsW4[64*32];   // 64 ci x 128 co (32 KB)
    __shared__ float4 ldsX4[128*8];   // [ci][pix] 128 x 32 (16 KB)

    const int t  = threadIdx.x;
    const int n0 = blockIdx.x * 32;
    const int b  = blockIdx.y;
    const int pj = blockIdx.z;
    const float* Wsrc = (pj == 0) ? Wq : (pj == 1) ? Wk : Wv;
    const float* bsrc = (pj == 0) ? bq : (pj == 1) ? bk : bv;

    for (int idx = t; idx < 128*32; idx += 256) {
        int pix = idx & 31, ci = idx >> 5;
        ((float*)ldsX4)[ci*32 + pix] = x[((size_t)b*C_ + ci)*N_ + n0 + pix];
    }

    const int co_g  = t & 31;   // co = co_g*4 .. +3
    const int pix_g = t >> 5;   // pix = pix_g*4 .. +3

    float4 bias = *(const float4*)(bsrc + co_g*4);
    float4 acc0 = bias, acc1 = bias, acc2 = bias, acc3 = bias;
    for (int half = 0; half < 2; ++half) {
        __syncthreads();   // guards x-stage (half 0) and ldsW readers (half 1)
        const float4* wsrc4 = (const float4*)(Wsrc + (size_t)half*64*C_);
        for (int idx = t; idx < 64*32; idx += 256) ldsW4[idx] = wsrc4[idx];
        __syncthreads();
        #pragma unroll 8
        for (int ci = 0; ci < 64; ++ci) {
            float4 xv = ldsX4[(half*64 + ci)*8 + pix_g];
            float4 wv = ldsW4[ci*32 + co_g];
            fma4(acc0, xv.x, wv);
            fma4(acc1, xv.y, wv);
            fma4(acc2, xv.z, wv);
            fma4(acc3, xv.w, wv);
        }
    }
    float4 accs[4] = {acc0, acc1, acc2, acc3};
    #pragma unroll
    for (int p = 0; p < 4; ++p) {
        int n = n0 + pix_g*4 + p;
        if (pj == 0) {
            *(float4*)(Qp + ((size_t)b*N_ + n)*C_ + co_g*4) = accs[p];
        } else {
            int y = n / W_, xx = n % W_;
            size_t rowb = (size_t)(y+PAD_)*HP_ + (xx+PAD_);
            int h = co_g >> 3;
            int u = ((pj == 1) ? 0 : 16) + (co_g & 7)*2;
            uint2 uu;
            uu.x = pack2(accs[p].x, accs[p].y);
            uu.y = pack2(accs[p].z, accs[p].w);
            *(uint2*)(KVp + ((size_t)(b*HEADS_+h)*HP2_ + rowb)*32 + u) = uu;
        }
    }
}

// ---------------------------------------------------------------------------
// Kernel 3: local attention, 4 threads per (pixel, head). (r11 exact.)
// QK on v_dot2_f32_bf16 with COMPENSATED q (hi+lo bf16, integer RNE pack).
// ---------------------------------------------------------------------------
__global__ __launch_bounds__(256, 3) void attn(
    const float* __restrict__ Qp, const uint* __restrict__ KVp,
    const float* __restrict__ PhiT, const float* __restrict__ log_alpha,
    const float* __restrict__ beta, float* __restrict__ AO)
{
    __shared__ uint4  kl[NHALO_*4];   // 12544 B
    __shared__ uint4  vl[NHALO_*4];   // 12544 B
    __shared__ float4 pl[NHALO_*4];   // 12544 B

    const int t  = threadIdx.x;
    const int h  = blockIdx.y;
    const int b  = blockIdx.z;
    const int bx = blockIdx.x;
    const int tile = ((bx & 7) * 18) + (bx >> 3);   // 144 = 8*18, bijective
    const int y0 = (tile / (W_/TILE_)) * TILE_;
    const int x0 = (tile % (W_/TILE_)) * TILE_;

    // stage K/V halo: one full 128B line per (row, head)
    const uint* kvb = KVp + (size_t)(b*HEADS_+h)*HP2_*32;
    for (int idx = t; idx < NHALO_*8; idx += 256) {
        int hp = idx >> 3, u4 = idx & 7;
        int hy = hp / HALO_, hx = hp % HALO_;
        size_t rowb = (size_t)(y0+hy)*HP_ + (x0+hx);
        uint4 val = *(const uint4*)(kvb + rowb*32 + u4*4);
        if (u4 < 4) kl[hp*4 + u4] = val;
        else        vl[hp*4 + (u4-4)] = val;
    }
    // stage phi halo (fp32)
    const float* pbase = PhiT + (size_t)b*HP2_*M_;
    for (int idx = t; idx < NHALO_*4; idx += 256) {
        int hp = idx >> 2, sb = idx & 3;
        int hy = hp / HALO_, hx = hp % HALO_;
        size_t rowb = (size_t)(y0+hy)*HP_ + (x0+hx);
        pl[idx] = *(const float4*)(pbase + rowb*M_ + sb*4);
    }
    __syncthreads();

    const int s  = t & 3;       // sub-lane: channels s*8.., phi dims s*4..
    const int p  = t >> 2;      // pixel 0..63
    const int qy = p >> 3, qx = p & 7;
    const int n  = (y0+qy)*W_ + (x0+qx);
    const bool c1 = (s & 1) != 0;
    const bool c2 = (s & 2) != 0;

    // q: load fp32; split q = q_hi + q_lo (both bf16, integer RNE pack).
    uint qh0, qh1, qh2, qh3, ql0, ql1, ql2, ql3;
    {
        const float* qptr = Qp + ((size_t)b*N_ + n)*C_ + h*HD_ + s*8;
        float4 q0 = ((const float4*)qptr)[0];
        float4 q1 = ((const float4*)qptr)[1];
        float qf[8] = {q0.x, q0.y, q0.z, q0.w, q1.x, q1.y, q1.z, q1.w};
        float rf[8];
        #pragma unroll
        for (int i = 0; i < 8; ++i)
            rf[i] = qf[i] - __uint_as_float(f2bf(qf[i]) << 16);
        qh0 = pack2(qf[0], qf[1]); qh1 = pack2(qf[2], qf[3]);
        qh2 = pack2(qf[4], qf[5]); qh3 = pack2(qf[6], qf[7]);
        ql0 = pack2(rf[0], rf[1]); ql1 = pack2(rf[2], rf[3]);
        ql2 = pack2(rf[4], rf[5]); ql3 = pack2(rf[6], rf[7]);
    }
    float4 pc = pl[((qy+PAD_)*HALO_ + (qx+PAD_))*4 + s];

    const float alpha = __expf(log_alpha[0]);
    const float scale = 0.17677669529663687f;                 // HD^-0.5
    const float gcoef = -beta[h] * alpha * 0.17677669529663687f; // -beta*alpha/sqrt(2M)

    auto partial = [&](int hp) -> float {
        uint4 kw = kl[(hp<<2) + s];
        float da = dot2bf(qh0, kw.x, 0.0f);
        float db = dot2bf(ql0, kw.x, 0.0f);
        da = dot2bf(qh1, kw.y, da);
        db = dot2bf(ql1, kw.y, db);
        da = dot2bf(qh2, kw.z, da);
        db = dot2bf(ql2, kw.z, db);
        da = dot2bf(qh3, kw.w, da);
        db = dot2bf(ql3, kw.w, db);
        float pdot = da + db;
        float4 pv = pl[(hp<<2) + s];
        float d0 = pc.x - pv.x, d1 = pc.y - pv.y;
        float d2 = pc.z - pv.z, d3 = pc.w - pv.w;
        float pdsq = fmaf(d0,d0, fmaf(d1,d1, fmaf(d2,d2, d3*d3)));
        return fmaf(pdot, scale, gcoef*pdsq);
    };

    float lp[13];
    float mx = -1e30f;

#define HPOS(KK) ((qy + (KK)/WIN_)*HALO_ + qx + ((KK)%WIN_))
#define LGROUP(G) { \
    float pr0 = partial(HPOS(4*(G)  )); \
    float pr1 = partial(HPOS(4*(G)+1)); \
    float pr2 = partial(HPOS(4*(G)+2)); \
    float pr3 = partial(HPOS(4*(G)+3)); \
    float Av = (c1 ? pr1 : pr0) + DPP_XOR1(c1 ? pr0 : pr1); \
    float Bv = (c1 ? pr3 : pr2) + DPP_XOR1(c1 ? pr2 : pr3); \
    float lg = (c2 ? Bv : Av) + DPP_XOR2(c2 ? Av : Bv); \
    lp[(G)] = lg; mx = fmaxf(mx, lg); }

    LGROUP(0) LGROUP(1) LGROUP(2) LGROUP(3) LGROUP(4) LGROUP(5)
    LGROUP(6) LGROUP(7) LGROUP(8) LGROUP(9) LGROUP(10) LGROUP(11)
    {   // kk = 48: all lanes hold it; only lane s==0 "owns" it
        float pr = partial(HPOS(48));
        pr += DPP_XOR1(pr);
        pr += DPP_XOR2(pr);
        lp[12] = pr; mx = fmaxf(mx, pr);
    }
    mx = fmaxf(mx, DPP_XOR1(mx));
    mx = fmaxf(mx, DPP_XOR2(mx));

    float ssum = 0.f;
#define EXPG(G) { float e = __expf(lp[(G)] - mx); lp[(G)] = e; ssum += e; }
    EXPG(0) EXPG(1) EXPG(2) EXPG(3) EXPG(4) EXPG(5)
    EXPG(6) EXPG(7) EXPG(8) EXPG(9) EXPG(10) EXPG(11)
    {
        float e = (s == 0) ? __expf(lp[12] - mx) : 0.f;
        lp[12] = e; ssum += e;
    }
    ssum += DPP_XOR1(ssum);
    ssum += DPP_XOR2(ssum);
    float inv = 1.0f / ssum;

    float4 o0 = make_float4(0.f,0.f,0.f,0.f);
    float4 o1 = make_float4(0.f,0.f,0.f,0.f);
#define PVPOS(KK, BC) { \
    float wgt = DPP_BCAST##BC(lp[(KK)>>2]); \
    uint4 vw = vl[(HPOS(KK)<<2) + s]; \
    o0.x = fmaf(wgt, bf_lo(vw.x), o0.x); \
    o0.y = fmaf(wgt, bf_hi(vw.x), o0.y); \
    o0.z = fmaf(wgt, bf_lo(vw.y), o0.z); \
    o0.w = fmaf(wgt, bf_hi(vw.y), o0.w); \
    o1.x = fmaf(wgt, bf_lo(vw.z), o1.x); \
    o1.y = fmaf(wgt, bf_hi(vw.z), o1.y); \
    o1.z = fmaf(wgt, bf_lo(vw.w), o1.z); \
    o1.w = fmaf(wgt, bf_hi(vw.w), o1.w); }

    PVPOS(0,0)  PVPOS(1,1)  PVPOS(2,2)  PVPOS(3,3)  PVPOS(4,0)  PVPOS(5,1)  PVPOS(6,2)
    PVPOS(7,3)  PVPOS(8,0)  PVPOS(9,1)  PVPOS(10,2) PVPOS(11,3) PVPOS(12,0) PVPOS(13,1)
    PVPOS(14,2) PVPOS(15,3) PVPOS(16,0) PVPOS(17,1) PVPOS(18,2) PVPOS(19,3) PVPOS(20,0)
    PVPOS(21,1) PVPOS(22,2) PVPOS(23,3) PVPOS(24,0) PVPOS(25,1) PVPOS(26,2) PVPOS(27,3)
    PVPOS(28,0) PVPOS(29,1) PVPOS(30,2) PVPOS(31,3) PVPOS(32,0) PVPOS(33,1) PVPOS(34,2)
    PVPOS(35,3) PVPOS(36,0) PVPOS(37,1) PVPOS(38,2) PVPOS(39,3) PVPOS(40,0) PVPOS(41,1)
    PVPOS(42,2) PVPOS(43,3) PVPOS(44,0) PVPOS(45,1) PVPOS(46,2) PVPOS(47,3) PVPOS(48,0)

    float* aop = AO + ((size_t)b*N_ + n)*C_ + h*HD_ + s*8;
    o0.x *= inv; o0.y *= inv; o0.z *= inv; o0.w *= inv;
    o1.x *= inv; o1.y *= inv; o1.z *= inv; o1.w *= inv;
    ((float4*)aop)[0] = o0;
    ((float4*)aop)[1] = o1;
}

// ---------------------------------------------------------------------------
// Kernel 4: output projection as K-paired bf16 dot2 GEMM, 32 pixels/block
// (576 blocks = 2.25/CU dispatch; LDS 40 KB -> 4 blocks/CU resident).
// AO (fp32) packed to bf16 pairs at stage; Wo packed at stage.
// Per ci2: 1 broadcast uint2 + 2 b128 reads feed 16 dot2.
// ---------------------------------------------------------------------------
__global__ __launch_bounds__(256, 4) void out_proj(
    const float* __restrict__ AO, const float* __restrict__ Wo,
    const float* __restrict__ bo, float* __restrict__ out)
{
    __shared__ uint ldsX[64*32];    // [ci2][pix] (8 KB)
    __shared__ uint ldsW[64*128];   // [ci2][co]  (32 KB)

    const int t  = threadIdx.x;
    const int b  = blockIdx.x / (N_/32);
    const int n0 = (blockIdx.x % (N_/32)) * 32;

    // stage X: AO[pix][4ci] float4 -> 2 packed pairs -> ldsX[ci2][pix]
    for (int idx = t; idx < 32*32; idx += 256) {
        int pix = idx & 31, c4 = idx >> 5;
        float4 v = ((const float4*)(AO + ((size_t)b*N_ + n0 + pix)*C_))[c4];
        ldsX[(c4*2+0)*32 + pix] = pack2(v.x, v.y);
        ldsX[(c4*2+1)*32 + pix] = pack2(v.z, v.w);
    }
    // stage W packed along ci pairs; coalesced over co
    for (int idx = t; idx < 64*128; idx += 256) {
        int ci2 = idx >> 7, co = idx & 127;
        ldsW[idx] = pack2(Wo[(size_t)(2*ci2)*C_ + co],
                          Wo[(size_t)(2*ci2+1)*C_ + co]);
    }
    __syncthreads();

    const int co_g  = t & 15;    // co  = co_g*8 .. +7
    const int pix_g = t >> 4;    // pix = pix_g*2 .. +1
    const int co0   = co_g * 8;

    float acc[8][2];
    #pragma unroll
    for (int i = 0; i < 8; ++i) {
        float bi = bo[co0 + i];
        acc[i][0] = bi; acc[i][1] = bi;
    }

    for (int ci2 = 0; ci2 < 64; ++ci2) {
        uint2 xv  = *(const uint2*)&ldsX[ci2*32 + pix_g*2];
        uint4 wv0 = *(const uint4*)&ldsW[ci2*128 + co0];
        uint4 wv1 = *(const uint4*)&ldsW[ci2*128 + co0 + 4];
        uint wa[8] = {wv0.x, wv0.y, wv0.z, wv0.w, wv1.x, wv1.y, wv1.z, wv1.w};
        #pragma unroll
        for (int i = 0; i < 8; ++i) {
            acc[i][0] = dot2bf(wa[i], xv.x, acc[i][0]);
            acc[i][1] = dot2bf(wa[i], xv.y, acc[i][1]);
        }
    }

    #pragma unroll
    for (int i = 0; i < 8; ++i) {
        *(float2*)(out + ((size_t)b*C_ + co0 + i)*N_ + n0 + pix_g*2) =
            make_float2(acc[i][0], acc[i][1]);
    }
}

// ---------------------------------------------------------------------------
extern "C" void kernel_launch(void* const* d_in, const int* in_sizes, int n_in,
                              void* d_out, int out_size, void* d_ws, size_t ws_size,
                              hipStream_t stream)
{
    const float* x    = (const float*)d_in[0];
    const float* phi  = (const float*)d_in[1];
    const float* Wq   = (const float*)d_in[2];
    const float* bq   = (const float*)d_in[3];
    const float* Wk   = (const float*)d_in[4];
    const float* bk   = (const float*)d_in[5];
    const float* Wv   = (const float*)d_in[6];
    const float* bv   = (const float*)d_in[7];
    const float* Wo   = (const float*)d_in[8];
    const float* bo   = (const float*)d_in[9];
    const float* la   = (const float*)d_in[10];
    const float* beta = (const float*)d_in[11];
    float* out = (float*)d_out;

    // workspace layout. AO aliases Qp: each attn thread reads exactly the q
    // slice it later writes as AO (same n, same head, same channels).
    float* ws   = (float*)d_ws;
    float* Qp   = ws;                                        // 9.44 MB fp32
    uint*  KVp  = (uint*)(Qp + (size_t)B_*N_*C_);            // 10.65 MB
    float* PhiT = (float*)(KVp + (size_t)B_*HEADS_*HP2_*32); // 1.33 MB
    float* AO   = Qp;                                        // aliased

    pad_fill<<<dim3((B_*HP2_ + 255)/256), dim3(256), 0, stream>>>(phi, bk, bv, KVp, PhiT);
    qkv_proj<<<dim3(N_/32, B_, 3), dim3(256), 0, stream>>>(x, Wq, bq, Wk, bk, Wv, bv, Qp, KVp);
    attn<<<dim3((H_/TILE_)*(W_/TILE_), HEADS_, B_), dim3(256), 0, stream>>>(Qp, KVp, PhiT, la, beta, AO);
    out_proj<<<dim3(B_*(N_/32)), dim3(256), 0, stream>>>(AO, Wo, bo, out);
}

// Round 15
// 65.960 us; speedup vs baseline: 1.3296x; 1.3031x over previous
//
#include <hip/hip_runtime.h>

typedef unsigned int uint;
typedef __attribute__((ext_vector_type(8))) short bf16x8;   // MFMA A/B frag (4 VGPR)
typedef __attribute__((ext_vector_type(4))) float f32x4;    // MFMA C/D frag

#define B_ 2
#define C_ 128
#define H_ 96
#define W_ 96
#define HEADS_ 4
#define HD_ 32
#define M_ 16
#define WIN_ 7
#define PAD_ 3
#define N_ (H_*W_)              // 9216
#define HP_ (H_+2*PAD_)         // 102
#define HP2_ (HP_*HP_)          // 10404
#define KW_ (WIN_*WIN_)         // 49
#define TILE_ 8                 // attn tile is 8x8 pixels
#define HALO_ (TILE_+WIN_-1)    // 14
#define NHALO_ (HALO_*HALO_)    // 196

static __device__ __forceinline__ uint f2bf(float f) {
    uint u = __float_as_uint(f);
    u = (u + 0x7fffu + ((u >> 16) & 1u)) >> 16;   // RNE to bf16 (integer, mode-independent)
    return u & 0xffffu;
}
static __device__ __forceinline__ uint pack2(float a, float b) {
    return f2bf(a) | (f2bf(b) << 16);
}
static __device__ __forceinline__ float bf_lo(uint u){ return __uint_as_float(u << 16); }
static __device__ __forceinline__ float bf_hi(uint u){ return __uint_as_float(u & 0xffff0000u); }

// HW bf16 pair-dot: D = a.bf16[0]*b.bf16[0] + a.bf16[1]*b.bf16[1] + c  (1 inst)
static __device__ __forceinline__ float dot2bf(uint a, uint b, float c) {
    float d;
    asm("v_dot2_f32_bf16 %0, %1, %2, %3" : "=v"(d) : "v"(a), "v"(b), "v"(c));
    return d;
}

// Intra-quad cross-lane via DPP quad_perm (VALU pipe) instead of __shfl_*.
template<int CTRL>
static __device__ __forceinline__ float dpp_mov(float v) {
    return __int_as_float(__builtin_amdgcn_update_dpp(
        0, __float_as_int(v), CTRL, 0xF, 0xF, false));
}
#define DPP_XOR1(v)  dpp_mov<0xB1>(v)   // [1,0,3,2]
#define DPP_XOR2(v)  dpp_mov<0x4E>(v)   // [2,3,0,1]
#define DPP_BCAST0(v) dpp_mov<0x00>(v)
#define DPP_BCAST1(v) dpp_mov<0x55>(v)
#define DPP_BCAST2(v) dpp_mov<0xAA>(v)
#define DPP_BCAST3(v) dpp_mov<0xFF>(v)

// LDS word swizzle for row-major [row][64 uint] tiles (G4: break the 256B-row
// bank alias). Applied identically on write and read; XOR value is a multiple
// of 4 so 4-word (b128) groups stay contiguous.
#define SWZ(row, c2) ((c2) ^ (((row) & 7) << 2))

// ---------------------------------------------------------------------------
// KVp layout (head-major, K/V interleaved, bf16 pairs):
//   KVp[((b*HEADS+h)*HP2 + row)*32 + u], u<16: K pair u, u>=16: V pair u-16.
// ---------------------------------------------------------------------------

// Kernel 1: fill padded borders of KVp with bias (= proj of zero input), and
// build PhiT: [B][102][102][16] fp32, border = 1.0   (r11 exact)
__global__ __launch_bounds__(256) void pad_fill(
    const float* __restrict__ phi, const float* __restrict__ bk, const float* __restrict__ bv,
    uint* __restrict__ KVp, float* __restrict__ PhiT)
{
    int idx = blockIdx.x * 256 + threadIdx.x;
    if (idx >= B_*HP2_) return;
    int b  = idx / HP2_;
    int pp = idx % HP2_;
    int py = pp / HP_, px = pp % HP_;
    bool interior = (py >= PAD_ && py < H_+PAD_ && px >= PAD_ && px < W_+PAD_);
    if (!interior) {
        #pragma unroll
        for (int h = 0; h < HEADS_; ++h) {
            size_t base = ((size_t)(b*HEADS_+h)*HP2_ + pp) * 32;
            #pragma unroll
            for (int q4i = 0; q4i < 4; ++q4i) {
                const float* kb8 = bk + h*HD_ + q4i*8;
                const float* vb8 = bv + h*HD_ + q4i*8;
                uint4 ku, vu;
                ku.x = pack2(kb8[0],kb8[1]); ku.y = pack2(kb8[2],kb8[3]);
                ku.z = pack2(kb8[4],kb8[5]); ku.w = pack2(kb8[6],kb8[7]);
                vu.x = pack2(vb8[0],vb8[1]); vu.y = pack2(vb8[2],vb8[3]);
                vu.z = pack2(vb8[4],vb8[5]); vu.w = pack2(vb8[6],vb8[7]);
                ((uint4*)(KVp + base))[q4i]     = ku;
                ((uint4*)(KVp + base))[4 + q4i] = vu;
            }
        }
    }
    size_t pb = ((size_t)b*HP2_ + pp) * M_;
    if (interior) {
        int y = py - PAD_, xx = px - PAD_;
        #pragma unroll
        for (int m = 0; m < M_; ++m)
            PhiT[pb + m] = phi[((size_t)b*M_ + m)*N_ + y*W_ + xx];
    } else {
        #pragma unroll
        for (int m = 0; m < M_; ++m) PhiT[pb + m] = 1.0f;
    }
}

// ---------------------------------------------------------------------------
// Kernel 2: Q/K/V projection on MFMA (16x16x32 bf16).
// D[co][pix]: A = W^T[co][ci] (LDS, swizzled), B = x^T[pix][ci] (LDS, swizzled).
// Block: 64 pixels x 128 co, 4 waves; wave w owns co-frags {2w,2w+1} x 4 pix-frags.
// Fragment mapping (m89-verified C/D; standard gfx950 A/B):
//   A: lane row = l&15,          k = (l>>4)*8 + j   (16B contiguous row-major)
//   B: lane col = l&15 (=pix),   k = (l>>4)*8 + j   (from [pix][ci] row-major)
//   D: lane col = l&15 (=pix),   row = (l>>4)*4 + reg (= co)
// ---------------------------------------------------------------------------
__global__ __launch_bounds__(256, 3) void qkv_proj(
    const float* __restrict__ x,
    const float* __restrict__ Wq, const float* __restrict__ bq,
    const float* __restrict__ Wk, const float* __restrict__ bk,
    const float* __restrict__ Wv, const float* __restrict__ bv,
    float* __restrict__ Qp, uint* __restrict__ KVp)
{
    __shared__ uint ldsA[128*64];   // W^T [co][ci2] bf16 pairs, swizzled (32 KB)
    __shared__ uint ldsB[64*64];    // x^T [pix][ci2] bf16 pairs, swizzled (16 KB)

    const int t  = threadIdx.x;
    const int n0 = blockIdx.x * 64;
    const int b  = blockIdx.y;
    const int pj = blockIdx.z;
    const float* Wsrc = (pj == 0) ? Wq : (pj == 1) ? Wk : Wv;
    const float* bsrc = (pj == 0) ? bq : (pj == 1) ? bk : bv;

    // stage W^T: read Wsrc[ci][co] coalesced over co; pack ci pairs
    for (int idx = t; idx < 128*64; idx += 256) {
        int co = idx & 127, c2 = idx >> 7;
        float w0 = Wsrc[(size_t)(2*c2  )*C_ + co];
        float w1 = Wsrc[(size_t)(2*c2+1)*C_ + co];
        ldsA[co*64 + SWZ(co, c2)] = pack2(w0, w1);
    }
    // stage x^T: read x[ci][n] coalesced over pix; pack ci pairs
    const float* xb = x + (size_t)b*C_*N_;
    for (int idx = t; idx < 64*64; idx += 256) {
        int pix = idx & 63, c2 = idx >> 6;
        float a0 = xb[(size_t)(2*c2  )*N_ + n0 + pix];
        float a1 = xb[(size_t)(2*c2+1)*N_ + n0 + pix];
        ldsB[pix*64 + SWZ(pix, c2)] = pack2(a0, a1);
    }
    __syncthreads();

    const int lane = t & 63, w = t >> 6;
    const int q = lane >> 4, r16 = lane & 15;
    const int sw = (r16 & 7) << 2;

    f32x4 acc[2][4];
    #pragma unroll
    for (int cf = 0; cf < 2; ++cf) {
        float4 b4 = *(const float4*)(bsrc + (2*w+cf)*16 + q*4);
        f32x4 bi = {b4.x, b4.y, b4.z, b4.w};
        #pragma unroll
        for (int pf = 0; pf < 4; ++pf) acc[cf][pf] = bi;
    }

    #pragma unroll
    for (int kk = 0; kk < 4; ++kk) {
        int kbase = kk*16 + q*4;
        bf16x8 af[2], bfr[4];
        #pragma unroll
        for (int cf = 0; cf < 2; ++cf) {
            int row = (2*w+cf)*16 + r16;
            af[cf] = *(const bf16x8*)&ldsA[row*64 + (kbase ^ sw)];
        }
        #pragma unroll
        for (int pf = 0; pf < 4; ++pf) {
            int row = pf*16 + r16;
            bfr[pf] = *(const bf16x8*)&ldsB[row*64 + (kbase ^ sw)];
        }
        #pragma unroll
        for (int cf = 0; cf < 2; ++cf)
            #pragma unroll
            for (int pf = 0; pf < 4; ++pf)
                acc[cf][pf] = __builtin_amdgcn_mfma_f32_16x16x32_bf16(
                    af[cf], bfr[pf], acc[cf][pf], 0, 0, 0);
    }

    if (pj == 0) {
        #pragma unroll
        for (int pf = 0; pf < 4; ++pf) {
            int n = n0 + pf*16 + r16;
            #pragma unroll
            for (int cf = 0; cf < 2; ++cf) {
                int co0 = (2*w+cf)*16 + q*4;
                *(f32x4*)(Qp + ((size_t)b*N_ + n)*C_ + co0) = acc[cf][pf];
            }
        }
    } else {
        int rowb[4];
        #pragma unroll
        for (int pf = 0; pf < 4; ++pf) {
            int n = n0 + pf*16 + r16;
            int y = n / W_, xx = n - y*W_;
            rowb[pf] = (y+PAD_)*HP_ + xx + PAD_;
        }
        const int ubase = (pj == 1) ? 0 : 16;
        #pragma unroll
        for (int cf = 0; cf < 2; ++cf) {
            int co0 = (2*w+cf)*16 + q*4;
            int h   = co0 >> 5;
            int u   = ubase + ((co0 & 31) >> 1);
            uint* kvb = KVp + (size_t)(b*HEADS_+h)*HP2_*32;
            #pragma unroll
            for (int pf = 0; pf < 4; ++pf) {
                uint2 uu;
                uu.x = pack2(acc[cf][pf][0], acc[cf][pf][1]);
                uu.y = pack2(acc[cf][pf][2], acc[cf][pf][3]);
                *(uint2*)(kvb + (size_t)rowb[pf]*32 + u) = uu;
            }
        }
    }
}

// ---------------------------------------------------------------------------
// Kernel 3: local attention, 4 threads per (pixel, head). (r11 exact.)
// QK on v_dot2_f32_bf16 with COMPENSATED q (hi+lo bf16, integer RNE pack).
// ---------------------------------------------------------------------------
__global__ __launch_bounds__(256, 3) void attn(
    const float* __restrict__ Qp, const uint* __restrict__ KVp,
    const float* __restrict__ PhiT, const float* __restrict__ log_alpha,
    const float* __restrict__ beta, float* __restrict__ AO)
{
    __shared__ uint4  kl[NHALO_*4];   // 12544 B
    __shared__ uint4  vl[NHALO_*4];   // 12544 B
    __shared__ float4 pl[NHALO_*4];   // 12544 B

    const int t  = threadIdx.x;
    const int h  = blockIdx.y;
    const int b  = blockIdx.z;
    const int bx = blockIdx.x;
    const int tile = ((bx & 7) * 18) + (bx >> 3);   // 144 = 8*18, bijective
    const int y0 = (tile / (W_/TILE_)) * TILE_;
    const int x0 = (tile % (W_/TILE_)) * TILE_;

    // stage K/V halo: one full 128B line per (row, head)
    const uint* kvb = KVp + (size_t)(b*HEADS_+h)*HP2_*32;
    for (int idx = t; idx < NHALO_*8; idx += 256) {
        int hp = idx >> 3, u4 = idx & 7;
        int hy = hp / HALO_, hx = hp % HALO_;
        size_t rowb = (size_t)(y0+hy)*HP_ + (x0+hx);
        uint4 val = *(const uint4*)(kvb + rowb*32 + u4*4);
        if (u4 < 4) kl[hp*4 + u4] = val;
        else        vl[hp*4 + (u4-4)] = val;
    }
    // stage phi halo (fp32)
    const float* pbase = PhiT + (size_t)b*HP2_*M_;
    for (int idx = t; idx < NHALO_*4; idx += 256) {
        int hp = idx >> 2, sb = idx & 3;
        int hy = hp / HALO_, hx = hp % HALO_;
        size_t rowb = (size_t)(y0+hy)*HP_ + (x0+hx);
        pl[idx] = *(const float4*)(pbase + rowb*M_ + sb*4);
    }
    __syncthreads();

    const int s  = t & 3;       // sub-lane: channels s*8.., phi dims s*4..
    const int p  = t >> 2;      // pixel 0..63
    const int qy = p >> 3, qx = p & 7;
    const int n  = (y0+qy)*W_ + (x0+qx);
    const bool c1 = (s & 1) != 0;
    const bool c2 = (s & 2) != 0;

    // q: load fp32; split q = q_hi + q_lo (both bf16, integer RNE pack).
    uint qh0, qh1, qh2, qh3, ql0, ql1, ql2, ql3;
    {
        const float* qptr = Qp + ((size_t)b*N_ + n)*C_ + h*HD_ + s*8;
        float4 q0 = ((const float4*)qptr)[0];
        float4 q1 = ((const float4*)qptr)[1];
        float qf[8] = {q0.x, q0.y, q0.z, q0.w, q1.x, q1.y, q1.z, q1.w};
        float rf[8];
        #pragma unroll
        for (int i = 0; i < 8; ++i)
            rf[i] = qf[i] - __uint_as_float(f2bf(qf[i]) << 16);
        qh0 = pack2(qf[0], qf[1]); qh1 = pack2(qf[2], qf[3]);
        qh2 = pack2(qf[4], qf[5]); qh3 = pack2(qf[6], qf[7]);
        ql0 = pack2(rf[0], rf[1]); ql1 = pack2(rf[2], rf[3]);
        ql2 = pack2(rf[4], rf[5]); ql3 = pack2(rf[6], rf[7]);
    }
    float4 pc = pl[((qy+PAD_)*HALO_ + (qx+PAD_))*4 + s];

    const float alpha = __expf(log_alpha[0]);
    const float scale = 0.17677669529663687f;                 // HD^-0.5
    const float gcoef = -beta[h] * alpha * 0.17677669529663687f; // -beta*alpha/sqrt(2M)

    auto partial = [&](int hp) -> float {
        uint4 kw = kl[(hp<<2) + s];
        float da = dot2bf(qh0, kw.x, 0.0f);
        float db = dot2bf(ql0, kw.x, 0.0f);
        da = dot2bf(qh1, kw.y, da);
        db = dot2bf(ql1, kw.y, db);
        da = dot2bf(qh2, kw.z, da);
        db = dot2bf(ql2, kw.z, db);
        da = dot2bf(qh3, kw.w, da);
        db = dot2bf(ql3, kw.w, db);
        float pdot = da + db;
        float4 pv = pl[(hp<<2) + s];
        float d0 = pc.x - pv.x, d1 = pc.y - pv.y;
        float d2 = pc.z - pv.z, d3 = pc.w - pv.w;
        float pdsq = fmaf(d0,d0, fmaf(d1,d1, fmaf(d2,d2, d3*d3)));
        return fmaf(pdot, scale, gcoef*pdsq);
    };

    float lp[13];
    float mx = -1e30f;

#define HPOS(KK) ((qy + (KK)/WIN_)*HALO_ + qx + ((KK)%WIN_))
#define LGROUP(G) { \
    float pr0 = partial(HPOS(4*(G)  )); \
    float pr1 = partial(HPOS(4*(G)+1)); \
    float pr2 = partial(HPOS(4*(G)+2)); \
    float pr3 = partial(HPOS(4*(G)+3)); \
    float Av = (c1 ? pr1 : pr0) + DPP_XOR1(c1 ? pr0 : pr1); \
    float Bv = (c1 ? pr3 : pr2) + DPP_XOR1(c1 ? pr2 : pr3); \
    float lg = (c2 ? Bv : Av) + DPP_XOR2(c2 ? Av : Bv); \
    lp[(G)] = lg; mx = fmaxf(mx, lg); }

    LGROUP(0) LGROUP(1) LGROUP(2) LGROUP(3) LGROUP(4) LGROUP(5)
    LGROUP(6) LGROUP(7) LGROUP(8) LGROUP(9) LGROUP(10) LGROUP(11)
    {   // kk = 48: all lanes hold it; only lane s==0 "owns" it
        float pr = partial(HPOS(48));
        pr += DPP_XOR1(pr);
        pr += DPP_XOR2(pr);
        lp[12] = pr; mx = fmaxf(mx, pr);
    }
    mx = fmaxf(mx, DPP_XOR1(mx));
    mx = fmaxf(mx, DPP_XOR2(mx));

    float ssum = 0.f;
#define EXPG(G) { float e = __expf(lp[(G)] - mx); lp[(G)] = e; ssum += e; }
    EXPG(0) EXPG(1) EXPG(2) EXPG(3) EXPG(4) EXPG(5)
    EXPG(6) EXPG(7) EXPG(8) EXPG(9) EXPG(10) EXPG(11)
    {
        float e = (s == 0) ? __expf(lp[12] - mx) : 0.f;
        lp[12] = e; ssum += e;
    }
    ssum += DPP_XOR1(ssum);
    ssum += DPP_XOR2(ssum);
    float inv = 1.0f / ssum;

    float4 o0 = make_float4(0.f,0.f,0.f,0.f);
    float4 o1 = make_float4(0.f,0.f,0.f,0.f);
#define PVPOS(KK, BC) { \
    float wgt = DPP_BCAST##BC(lp[(KK)>>2]); \
    uint4 vw = vl[(HPOS(KK)<<2) + s]; \
    o0.x = fmaf(wgt, bf_lo(vw.x), o0.x); \
    o0.y = fmaf(wgt, bf_hi(vw.x), o0.y); \
    o0.z = fmaf(wgt, bf_lo(vw.y), o0.z); \
    o0.w = fmaf(wgt, bf_hi(vw.y), o0.w); \
    o1.x = fmaf(wgt, bf_lo(vw.z), o1.x); \
    o1.y = fmaf(wgt, bf_hi(vw.z), o1.y); \
    o1.z = fmaf(wgt, bf_lo(vw.w), o1.z); \
    o1.w = fmaf(wgt, bf_hi(vw.w), o1.w); }

    PVPOS(0,0)  PVPOS(1,1)  PVPOS(2,2)  PVPOS(3,3)  PVPOS(4,0)  PVPOS(5,1)  PVPOS(6,2)
    PVPOS(7,3)  PVPOS(8,0)  PVPOS(9,1)  PVPOS(10,2) PVPOS(11,3) PVPOS(12,0) PVPOS(13,1)
    PVPOS(14,2) PVPOS(15,3) PVPOS(16,0) PVPOS(17,1) PVPOS(18,2) PVPOS(19,3) PVPOS(20,0)
    PVPOS(21,1) PVPOS(22,2) PVPOS(23,3) PVPOS(24,0) PVPOS(25,1) PVPOS(26,2) PVPOS(27,3)
    PVPOS(28,0) PVPOS(29,1) PVPOS(30,2) PVPOS(31,3) PVPOS(32,0) PVPOS(33,1) PVPOS(34,2)
    PVPOS(35,3) PVPOS(36,0) PVPOS(37,1) PVPOS(38,2) PVPOS(39,3) PVPOS(40,0) PVPOS(41,1)
    PVPOS(42,2) PVPOS(43,3) PVPOS(44,0) PVPOS(45,1) PVPOS(46,2) PVPOS(47,3) PVPOS(48,0)

    float* aop = AO + ((size_t)b*N_ + n)*C_ + h*HD_ + s*8;
    o0.x *= inv; o0.y *= inv; o0.z *= inv; o0.w *= inv;
    o1.x *= inv; o1.y *= inv; o1.z *= inv; o1.w *= inv;
    ((float4*)aop)[0] = o0;
    ((float4*)aop)[1] = o1;
}

// ---------------------------------------------------------------------------
// Kernel 4: output projection on MFMA. Same template as qkv_proj:
// A = Wo^T[co][ci] (LDS swizzled), B = AO[pix][ci] packed bf16 (LDS swizzled),
// D[co][pix] -> out[b][co][n] (lane-contiguous n, coalesced).
// ---------------------------------------------------------------------------
__global__ __launch_bounds__(256, 3) void out_proj(
    const float* __restrict__ AO, const float* __restrict__ Wo,
    const float* __restrict__ bo, float* __restrict__ out)
{
    __shared__ uint ldsA[128*64];   // Wo^T (32 KB)
    __shared__ uint ldsB[64*64];    // AO   (16 KB)

    const int t  = threadIdx.x;
    const int b  = blockIdx.x / (N_/64);
    const int n0 = (blockIdx.x % (N_/64)) * 64;

    for (int idx = t; idx < 128*64; idx += 256) {
        int co = idx & 127, c2 = idx >> 7;
        float w0 = Wo[(size_t)(2*c2  )*C_ + co];
        float w1 = Wo[(size_t)(2*c2+1)*C_ + co];
        ldsA[co*64 + SWZ(co, c2)] = pack2(w0, w1);
    }
    // AO is [n][C] fp32: pack to bf16 pairs into [pix][ci2]
    for (int idx = t; idx < 64*32; idx += 256) {
        int pix = idx >> 5, c4 = idx & 31;
        float4 v = ((const float4*)(AO + ((size_t)b*N_ + n0 + pix)*C_))[c4];
        ldsB[pix*64 + SWZ(pix, 2*c4  )] = pack2(v.x, v.y);
        ldsB[pix*64 + SWZ(pix, 2*c4+1)] = pack2(v.z, v.w);
    }
    __syncthreads();

    const int lane = t & 63, w = t >> 6;
    const int q = lane >> 4, r16 = lane & 15;
    const int sw = (r16 & 7) << 2;

    f32x4 acc[2][4];
    #pragma unroll
    for (int cf = 0; cf < 2; ++cf) {
        float4 b4 = *(const float4*)(bo + (2*w+cf)*16 + q*4);
        f32x4 bi = {b4.x, b4.y, b4.z, b4.w};
        #pragma unroll
        for (int pf = 0; pf < 4; ++pf) acc[cf][pf] = bi;
    }

    #pragma unroll
    for (int kk = 0; kk < 4; ++kk) {
        int kbase = kk*16 + q*4;
        bf16x8 af[2], bfr[4];
        #pragma unroll
        for (int cf = 0; cf < 2; ++cf) {
            int row = (2*w+cf)*16 + r16;
            af[cf] = *(const bf16x8*)&ldsA[row*64 + (kbase ^ sw)];
        }
        #pragma unroll
        for (int pf = 0; pf < 4; ++pf) {
            int row = pf*16 + r16;
            bfr[pf] = *(const bf16x8*)&ldsB[row*64 + (kbase ^ sw)];
        }
        #pragma unroll
        for (int cf = 0; cf < 2; ++cf)
            #pragma unroll
            for (int pf = 0; pf < 4; ++pf)
                acc[cf][pf] = __builtin_amdgcn_mfma_f32_16x16x32_bf16(
                    af[cf], bfr[pf], acc[cf][pf], 0, 0, 0);
    }

    #pragma unroll
    for (int cf = 0; cf < 2; ++cf) {
        #pragma unroll
        for (int rr = 0; rr < 4; ++rr) {
            int co = (2*w+cf)*16 + q*4 + rr;
            float* orow = out + ((size_t)b*C_ + co)*N_ + n0;
            #pragma unroll
            for (int pf = 0; pf < 4; ++pf)
                orow[pf*16 + r16] = acc[cf][pf][rr];
        }
    }
}

// ---------------------------------------------------------------------------
extern "C" void kernel_launch(void* const* d_in, const int* in_sizes, int n_in,
                              void* d_out, int out_size, void* d_ws, size_t ws_size,
                              hipStream_t stream)
{
    const float* x    = (const float*)d_in[0];
    const float* phi  = (const float*)d_in[1];
    const float* Wq   = (const float*)d_in[2];
    const float* bq   = (const float*)d_in[3];
    const float* Wk   = (const float*)d_in[4];
    const float* bk   = (const float*)d_in[5];
    const float* Wv   = (const float*)d_in[6];
    const float* bv   = (const float*)d_in[7];
    const float* Wo   = (const float*)d_in[8];
    const float* bo   = (const float*)d_in[9];
    const float* la   = (const float*)d_in[10];
    const float* beta = (const float*)d_in[11];
    float* out = (float*)d_out;

    // workspace layout. AO aliases Qp: each attn thread reads exactly the q
    // slice it later writes as AO (same n, same head, same channels).
    float* ws   = (float*)d_ws;
    float* Qp   = ws;                                        // 9.44 MB fp32
    uint*  KVp  = (uint*)(Qp + (size_t)B_*N_*C_);            // 10.65 MB
    float* PhiT = (float*)(KVp + (size_t)B_*HEADS_*HP2_*32); // 1.33 MB
    float* AO   = Qp;                                        // aliased

    pad_fill<<<dim3((B_*HP2_ + 255)/256), dim3(256), 0, stream>>>(phi, bk, bv, KVp, PhiT);
    qkv_proj<<<dim3(N_/64, B_, 3), dim3(256), 0, stream>>>(x, Wq, bq, Wk, bk, Wv, bv, Qp, KVp);
    attn<<<dim3((H_/TILE_)*(W_/TILE_), HEADS_, B_), dim3(256), 0, stream>>>(Qp, KVp, PhiT, la, beta, AO);
    out_proj<<<dim3(B_*(N_/64)), dim3(256), 0, stream>>>(AO, Wo, bo, out);
}